// Round 1
// baseline (113.187 us; speedup 1.0000x reference)
//
#include <hip/hip_runtime.h>
#include <math.h>

// SDF over 31 spheres: out[i] = min_s( ||p_i - c_s|| - r_s )
// points: [N,3] f32 (AoS), centers: [S,3] f32, radii: [S] f32, out: [N] f32.
//
// Layout trick: 4 points == 12 floats == 3 float4 -> fully coalesced 16B loads.
// Sphere constants are wave-uniform -> scalar loads (s_load), free on VALU pipe.

template <int S>
__global__ __launch_bounds__(256) void sdf_kernel_fixed(
    const float* __restrict__ points,
    const float* __restrict__ centers,
    const float* __restrict__ radii,
    float* __restrict__ out,
    int ngroups, int npoints)
{
    int t = blockIdx.x * blockDim.x + threadIdx.x;
    if (t >= ngroups) return;

    int base = 4 * t;
    float x[4], y[4], z[4];

    if (base + 4 <= npoints) {
        const float4* p4 = reinterpret_cast<const float4*>(points) + 3ull * (unsigned)t;
        float4 a = p4[0];
        float4 b = p4[1];
        float4 c = p4[2];
        x[0] = a.x; y[0] = a.y; z[0] = a.z;
        x[1] = a.w; y[1] = b.x; z[1] = b.y;
        x[2] = b.z; y[2] = b.w; z[2] = c.x;
        x[3] = c.y; y[3] = c.z; z[3] = c.w;
    } else {
        // tail: guarded scalar loads (duplicate last point for lanes past end)
        for (int j = 0; j < 4; ++j) {
            int i = base + j;
            int ii = (i < npoints) ? i : (npoints - 1);
            x[j] = points[3 * ii + 0];
            y[j] = points[3 * ii + 1];
            z[j] = points[3 * ii + 2];
        }
    }

    float m0 = 1e30f, m1 = 1e30f, m2 = 1e30f, m3 = 1e30f;

#pragma unroll
    for (int s = 0; s < S; ++s) {
        float cx = centers[3 * s + 0];
        float cy = centers[3 * s + 1];
        float cz = centers[3 * s + 2];
        float r  = radii[s];

        {
            float dx = x[0] - cx, dy = y[0] - cy, dz = z[0] - cz;
            float sq = fmaf(dx, dx, fmaf(dy, dy, dz * dz));
            m0 = fminf(m0, __builtin_amdgcn_sqrtf(sq) - r);
        }
        {
            float dx = x[1] - cx, dy = y[1] - cy, dz = z[1] - cz;
            float sq = fmaf(dx, dx, fmaf(dy, dy, dz * dz));
            m1 = fminf(m1, __builtin_amdgcn_sqrtf(sq) - r);
        }
        {
            float dx = x[2] - cx, dy = y[2] - cy, dz = z[2] - cz;
            float sq = fmaf(dx, dx, fmaf(dy, dy, dz * dz));
            m2 = fminf(m2, __builtin_amdgcn_sqrtf(sq) - r);
        }
        {
            float dx = x[3] - cx, dy = y[3] - cy, dz = z[3] - cz;
            float sq = fmaf(dx, dx, fmaf(dy, dy, dz * dz));
            m3 = fminf(m3, __builtin_amdgcn_sqrtf(sq) - r);
        }
    }

    if (base + 4 <= npoints) {
        *reinterpret_cast<float4*>(out + base) = make_float4(m0, m1, m2, m3);
    } else {
        float mm[4] = {m0, m1, m2, m3};
        for (int j = 0; j < 4; ++j)
            if (base + j < npoints) out[base + j] = mm[j];
    }
}

// Runtime-S fallback (same structure, no unroll guarantee).
__global__ __launch_bounds__(256) void sdf_kernel_generic(
    const float* __restrict__ points,
    const float* __restrict__ centers,
    const float* __restrict__ radii,
    float* __restrict__ out,
    int ngroups, int npoints, int S)
{
    int t = blockIdx.x * blockDim.x + threadIdx.x;
    if (t >= ngroups) return;

    int base = 4 * t;
    float x[4], y[4], z[4];

    if (base + 4 <= npoints) {
        const float4* p4 = reinterpret_cast<const float4*>(points) + 3ull * (unsigned)t;
        float4 a = p4[0];
        float4 b = p4[1];
        float4 c = p4[2];
        x[0] = a.x; y[0] = a.y; z[0] = a.z;
        x[1] = a.w; y[1] = b.x; z[1] = b.y;
        x[2] = b.z; y[2] = b.w; z[2] = c.x;
        x[3] = c.y; y[3] = c.z; z[3] = c.w;
    } else {
        for (int j = 0; j < 4; ++j) {
            int i = base + j;
            int ii = (i < npoints) ? i : (npoints - 1);
            x[j] = points[3 * ii + 0];
            y[j] = points[3 * ii + 1];
            z[j] = points[3 * ii + 2];
        }
    }

    float m[4] = {1e30f, 1e30f, 1e30f, 1e30f};
    for (int s = 0; s < S; ++s) {
        float cx = centers[3 * s + 0];
        float cy = centers[3 * s + 1];
        float cz = centers[3 * s + 2];
        float r  = radii[s];
#pragma unroll
        for (int j = 0; j < 4; ++j) {
            float dx = x[j] - cx, dy = y[j] - cy, dz = z[j] - cz;
            float sq = fmaf(dx, dx, fmaf(dy, dy, dz * dz));
            m[j] = fminf(m[j], __builtin_amdgcn_sqrtf(sq) - r);
        }
    }

    if (base + 4 <= npoints) {
        *reinterpret_cast<float4*>(out + base) = make_float4(m[0], m[1], m[2], m[3]);
    } else {
        for (int j = 0; j < 4; ++j)
            if (base + j < npoints) out[base + j] = m[j];
    }
}

extern "C" void kernel_launch(void* const* d_in, const int* in_sizes, int n_in,
                              void* d_out, int out_size, void* d_ws, size_t ws_size,
                              hipStream_t stream) {
    const float* points  = (const float*)d_in[0];
    const float* centers = (const float*)d_in[1];
    const float* radii   = (const float*)d_in[2];
    float* out = (float*)d_out;

    int npoints = in_sizes[0] / 3;
    int S       = in_sizes[2];
    int ngroups = (npoints + 3) / 4;

    const int block = 256;
    int grid = (ngroups + block - 1) / block;

    if (S == 31) {
        sdf_kernel_fixed<31><<<grid, block, 0, stream>>>(
            points, centers, radii, out, ngroups, npoints);
    } else {
        sdf_kernel_generic<<<grid, block, 0, stream>>>(
            points, centers, radii, out, ngroups, npoints, S);
    }
}

// Round 2
// 107.355 us; speedup vs baseline: 1.0543x; 1.0543x over previous
//
#include <hip/hip_runtime.h>
#include <math.h>

// SDF over S spheres: out[i] = min_s( ||p_i - c_s|| - r_s )
// points: [N,3] f32 AoS, centers: [S,3] f32, radii: [S] f32, out: [N] f32.
//
// Round-2 structure:
//  - 8 points/thread: 6 coalesced float4 loads, 2 float4 stores.
//  - point PAIRS as <2 x float> -> backend emits v_pk_{add,mul,fma}_f32
//    (packed fp32, 2 ops/issue on gfx90a+) for the sub/fma distance math.
//  - spheres processed two at a time; fminf(fminf(m,d0),d1) folds to
//    v_min3_f32 (1 issue per point per sphere-pair).
//  - sqrt stays scalar v_sqrt_f32 (quarter-rate trans pipe, not the limiter).

typedef float v2f __attribute__((ext_vector_type(2)));

template <int S>
__global__ __launch_bounds__(256) void sdf_kernel_fixed(
    const float* __restrict__ points,
    const float* __restrict__ centers,
    const float* __restrict__ radii,
    float* __restrict__ out,
    int ngroups, int npoints)
{
    int t = blockIdx.x * blockDim.x + threadIdx.x;
    if (t >= ngroups) return;

    int base = 8 * t;

    v2f X[4], Y[4], Z[4];   // 4 point-pairs

    if (base + 8 <= npoints) {
        const float4* p4 = reinterpret_cast<const float4*>(points) + 6ull * (unsigned)t;
        float4 q0 = p4[0];
        float4 q1 = p4[1];
        float4 q2 = p4[2];
        float4 q3 = p4[3];
        float4 q4 = p4[4];
        float4 q5 = p4[5];
        // floats f[0..23]; point j = (f[3j], f[3j+1], f[3j+2])
        // pair k holds points 2k, 2k+1:
        X[0].x = q0.x; Y[0].x = q0.y; Z[0].x = q0.z;   // p0
        X[0].y = q0.w; Y[0].y = q1.x; Z[0].y = q1.y;   // p1
        X[1].x = q1.z; Y[1].x = q1.w; Z[1].x = q2.x;   // p2
        X[1].y = q2.y; Y[1].y = q2.z; Z[1].y = q2.w;   // p3
        X[2].x = q3.x; Y[2].x = q3.y; Z[2].x = q3.z;   // p4
        X[2].y = q3.w; Y[2].y = q4.x; Z[2].y = q4.y;   // p5
        X[3].x = q4.z; Y[3].x = q4.w; Z[3].x = q5.x;   // p6
        X[3].y = q5.y; Y[3].y = q5.z; Z[3].y = q5.w;   // p7
    } else {
        for (int k = 0; k < 4; ++k) {
            for (int h = 0; h < 2; ++h) {
                int i = base + 2 * k + h;
                int ii = (i < npoints) ? i : (npoints - 1);
                X[k][h] = points[3 * ii + 0];
                Y[k][h] = points[3 * ii + 1];
                Z[k][h] = points[3 * ii + 2];
            }
        }
    }

    v2f m[4];
#pragma unroll
    for (int k = 0; k < 4; ++k) { m[k].x = 1e30f; m[k].y = 1e30f; }

    // Spheres two at a time -> v_min3_f32 accumulation.
#pragma unroll
    for (int s = 0; s + 1 < S; s += 2) {
        float cx0 = centers[3 * s + 0], cy0 = centers[3 * s + 1], cz0 = centers[3 * s + 2];
        float r0  = radii[s];
        float cx1 = centers[3 * s + 3], cy1 = centers[3 * s + 4], cz1 = centers[3 * s + 5];
        float r1  = radii[s + 1];

#pragma unroll
        for (int k = 0; k < 4; ++k) {
            v2f dx0 = X[k] - cx0, dy0 = Y[k] - cy0, dz0 = Z[k] - cz0;
            v2f sq0 = dx0 * dx0 + dy0 * dy0 + dz0 * dz0;   // -> v_pk_fma_f32 chain
            v2f dx1 = X[k] - cx1, dy1 = Y[k] - cy1, dz1 = Z[k] - cz1;
            v2f sq1 = dx1 * dx1 + dy1 * dy1 + dz1 * dz1;

            float d0x = __builtin_amdgcn_sqrtf(sq0.x) - r0;
            float d0y = __builtin_amdgcn_sqrtf(sq0.y) - r0;
            float d1x = __builtin_amdgcn_sqrtf(sq1.x) - r1;
            float d1y = __builtin_amdgcn_sqrtf(sq1.y) - r1;

            m[k].x = fminf(fminf(m[k].x, d0x), d1x);   // -> v_min3_f32
            m[k].y = fminf(fminf(m[k].y, d0y), d1y);
        }
    }
    if (S & 1) {
        int s = S - 1;
        float cx = centers[3 * s + 0], cy = centers[3 * s + 1], cz = centers[3 * s + 2];
        float r  = radii[s];
#pragma unroll
        for (int k = 0; k < 4; ++k) {
            v2f dx = X[k] - cx, dy = Y[k] - cy, dz = Z[k] - cz;
            v2f sq = dx * dx + dy * dy + dz * dz;
            m[k].x = fminf(m[k].x, __builtin_amdgcn_sqrtf(sq.x) - r);
            m[k].y = fminf(m[k].y, __builtin_amdgcn_sqrtf(sq.y) - r);
        }
    }

    if (base + 8 <= npoints) {
        float4* o4 = reinterpret_cast<float4*>(out + base);
        o4[0] = make_float4(m[0].x, m[0].y, m[1].x, m[1].y);
        o4[1] = make_float4(m[2].x, m[2].y, m[3].x, m[3].y);
    } else {
        for (int k = 0; k < 4; ++k) {
            for (int h = 0; h < 2; ++h) {
                int i = base + 2 * k + h;
                if (i < npoints) out[i] = m[k][h];
            }
        }
    }
}

// Runtime-S fallback.
__global__ __launch_bounds__(256) void sdf_kernel_generic(
    const float* __restrict__ points,
    const float* __restrict__ centers,
    const float* __restrict__ radii,
    float* __restrict__ out,
    int npoints, int S)
{
    int i = blockIdx.x * blockDim.x + threadIdx.x;
    if (i >= npoints) return;
    float x = points[3 * i + 0];
    float y = points[3 * i + 1];
    float z = points[3 * i + 2];
    float m = 1e30f;
    for (int s = 0; s < S; ++s) {
        float dx = x - centers[3 * s + 0];
        float dy = y - centers[3 * s + 1];
        float dz = z - centers[3 * s + 2];
        float sq = fmaf(dx, dx, fmaf(dy, dy, dz * dz));
        m = fminf(m, __builtin_amdgcn_sqrtf(sq) - radii[s]);
    }
    out[i] = m;
}

extern "C" void kernel_launch(void* const* d_in, const int* in_sizes, int n_in,
                              void* d_out, int out_size, void* d_ws, size_t ws_size,
                              hipStream_t stream) {
    const float* points  = (const float*)d_in[0];
    const float* centers = (const float*)d_in[1];
    const float* radii   = (const float*)d_in[2];
    float* out = (float*)d_out;

    int npoints = in_sizes[0] / 3;
    int S       = in_sizes[2];

    const int block = 256;

    if (S == 31) {
        int ngroups = (npoints + 7) / 8;
        int grid = (ngroups + block - 1) / block;
        sdf_kernel_fixed<31><<<grid, block, 0, stream>>>(
            points, centers, radii, out, ngroups, npoints);
    } else {
        int grid = (npoints + block - 1) / block;
        sdf_kernel_generic<<<grid, block, 0, stream>>>(
            points, centers, radii, out, npoints, S);
    }
}